// Round 11
// baseline (132.579 us; speedup 1.0000x reference)
//
#include <hip/hip_runtime.h>
#include <hip/hip_bf16.h>
#include <math.h>

// MMD (InfoVAE RBF kernel), N=8192, D=128, fp32 in, scalar fp32 out.
//
// Round 11: persistent blocks + B-from-L2 + full-K A panel + fused finish.
//   r10 analysis: LDS read pipe was the top floor (4x read amplification:
//   every wave pulled both panels through LDS). Changes:
//   - B operands load global->VGPR directly (Z is L2-resident, 4 MB);
//     LDS holds only the A panel, full K (32 KB), staged via
//     global_load_lds(16B, offset arg ALWAYS 0 - r8/r9 bug) with XOR
//     swizzle (lds chunk c of row r holds global chunk c^(r&15)).
//   - Persistent: grid 768 (3 blocks/CU), contiguous chunks of 10-11 tiles
//     of the upper triangle (8256 tiles), walking J along row I ->
//     A panel + rowN registers reused across the walk; NO barriers in the
//     common-case tile loop (only around rare A restages) -> waves free-run.
//   - Per-thread fp64 accumulation across tiles (weights +-1/+-2 applied
//     per tile), ONE atomic per block; finish fused via completion counter
//     (r8's fused reduction produced bit-identical results to r9's separate
//     finish -> exonerated; the r8/r9 bug was the DMA offset arg).
//   Numerics (r3-r10): bf16 MFMA arg noise zero-mean -> ~2e-9 MMD shift;
//   exp2 HW bias cancels in +1+1-2; fp32 per-tile partials (<=16); fp64
//   across tiles/blocks. absmax held at 5.96e-8 (threshold 7.15e-8).

#define NN 8192
#define DD 128
#define TZ 16384
#define TILES 128
#define NTILES (TILES * (TILES + 1) / 2)   // 8256
#define GRID 768                           // 3 blocks/CU x 256 CU

typedef __attribute__((ext_vector_type(8))) short bf16x8;
typedef __attribute__((ext_vector_type(4))) float f32x4;
typedef __attribute__((ext_vector_type(2))) float f32x2;

#if __has_builtin(__builtin_amdgcn_exp2f)
#define EXP2F __builtin_amdgcn_exp2f
#else
#define EXP2F exp2f
#endif

constexpr float LOG2E = 0x1.715476p+0f;
constexpr float S2 = LOG2E / 8192.0f;              // 2*log2e/16384

// ---- ws layout ----
constexpr size_t WS_CTR  = 512;
constexpr size_t WS_NORM = 768;
constexpr size_t WS_Z    = WS_NORM + (size_t)TZ * sizeof(float);

__device__ __forceinline__ void gload_lds16(const void* g, void* l) {
  __builtin_amdgcn_global_load_lds(
      (const __attribute__((address_space(1))) void*)g,
      (__attribute__((address_space(3))) void*)l, 16, 0, 0);
}

__global__ __launch_bounds__(256) void prep(
    const float* __restrict__ X, const float* __restrict__ Y,
    __hip_bfloat16* __restrict__ Z, float* __restrict__ normZ,
    double* __restrict__ sums, unsigned* __restrict__ ctr) {
  if (blockIdx.x == 0) {
    if (threadIdx.x < 64) sums[threadIdx.x] = 0.0;
    if (threadIdx.x == 64) *ctr = 0u;
  }

  const int row = blockIdx.x * 4 + (threadIdx.x >> 6);
  const int lane = threadIdx.x & 63;
  const float* __restrict__ src =
      (row < NN) ? (X + (size_t)row * DD) : (Y + (size_t)(row - NN) * DD);
  const float2 v = *reinterpret_cast<const float2*>(src + 2 * lane);

  float n = v.x * v.x + v.y * v.y;
  *reinterpret_cast<__hip_bfloat162*>(Z + (size_t)row * DD + 2 * lane) =
      __hip_bfloat162{__float2bfloat16(v.x), __float2bfloat16(v.y)};

#pragma unroll
  for (int o = 32; o > 0; o >>= 1) n += __shfl_down(n, o);
  if (lane == 0) normZ[row] = n * (-LOG2E / 16384.0f);  // pre-scaled
}

__device__ __forceinline__ int tri_start(int i) {
  return i * TILES - (i * (i - 1)) / 2;
}

__global__ __launch_bounds__(256, 3) void mmd_mfma(
    const __hip_bfloat16* __restrict__ Z, const float* __restrict__ normZ,
    double* __restrict__ sums, unsigned* __restrict__ ctr,
    float* __restrict__ out) {
  __shared__ alignas(16) char ldsA[32768];       // A panel, full K, swizzled
  __shared__ double red[4];
  __shared__ bool amLast;

  const int b = blockIdx.x;
  // Contiguous chunk: blocks 0..575 take 11 tiles, 576..767 take 10.
  const int t0 = b * 10 + min(b, 576);
  const int nt = (b < 576) ? 11 : 10;

  // Unrank t0 -> (I,J), I<=J<128.
  int I = (int)((257.0 - sqrt(257.0 * 257.0 - 8.0 * (double)t0)) * 0.5);
  if (I > 127) I = 127;
  if (I < 0) I = 0;
  while (I < 127 && tri_start(I + 1) <= t0) ++I;
  while (I > 0 && tri_start(I) > t0) --I;
  int J = I + (t0 - tri_start(I));

  const int tid = threadIdx.x;
  const int lane = tid & 63, wave = tid >> 6;
  const int wr = wave >> 1, wc = wave & 1;       // 2x2 wave grid over 128x128
  const int lr = lane & 15, quad = lane >> 4;    // MFMA lane decomposition

  const char* Zb = (const char*)Z;

  // A staging (wave w stages segments s = 4k + w, k=0..7; LDS dest
  // ldsA + s*1024 + lane*16; flat chunk f = s*64+lane; row=f>>4, c=lane&15,
  // global chunk g = c ^ (row&15), row&15 = (s&3)*4 + (lane>>4) = w*4+quad).
  const int rowlow = wave * 4 + quad;            // (row&15) for this wave's segs
  const int gOffA = rowlow * 256 + ((lane & 15) ^ rowlow) * 16;  // per-lane
  char* ldsW = ldsA + wave * 1024;               // wave-uniform base for k=0

  // A-frag read: row = wr*64 + i*16 + lr (row&15 == lr);
  // lds addr = row*256 + ((p*8 + ks*4 + quad) ^ lr)*16.
  const int aBase = (wr * 64 + lr) * 256;
  const int aSw = lr;

  double local = 0.0;
  bool needA = true;
  f32x2 ar01[4], ar23[4];                        // rowN regs (refresh w/ A)
  const f32x2 s2v = {S2, S2};

  for (int it = 0; it < nt; ++it) {
    // Per-tile B pointers / colN.
    const char* pB = Zb + (size_t)(J * 128 + wc * 64 + lr) * 256 + quad * 16;
    float cn[4];
#pragma unroll
    for (int j = 0; j < 4; ++j) cn[j] = normZ[J * 128 + wc * 64 + j * 16 + lr];

    if (needA) {
      __syncthreads();  // all waves done reading old A
#pragma unroll
      for (int k = 0; k < 8; ++k)
        gload_lds16(Zb + (size_t)I * 32768 + k * 4096 + gOffA,
                    ldsW + k * 4096);
      // rowN registers: rowN[I*128 + wr*64 + i*16 + quad*4 + r]
#pragma unroll
      for (int i = 0; i < 4; ++i) {
        const float* p = normZ + I * 128 + wr * 64 + i * 16 + quad * 4;
        const float2 v01 = *reinterpret_cast<const float2*>(p);
        const float2 v23 = *reinterpret_cast<const float2*>(p + 2);
        ar01[i] = (f32x2){v01.x, v01.y};
        ar23[i] = (f32x2){v23.x, v23.y};
      }
      needA = false;
      __syncthreads();  // vmcnt drain: A resident
    }

    f32x4 acc[4][4] = {};
#pragma unroll
    for (int p = 0; p < 2; ++p) {
      bf16x8 bq[2][4];
#pragma unroll
      for (int ks = 0; ks < 2; ++ks)
#pragma unroll
        for (int j = 0; j < 4; ++j)
          bq[ks][j] = *reinterpret_cast<const bf16x8*>(
              pB + j * 4096 + p * 128 + ks * 64);
#pragma unroll
      for (int ks = 0; ks < 2; ++ks) {
        const int csw = ((p * 8 + ks * 4 + quad) ^ aSw) * 16;
        bf16x8 a[4];
#pragma unroll
        for (int i = 0; i < 4; ++i)
          a[i] = *reinterpret_cast<const bf16x8*>(&ldsA[aBase + i * 4096 + csw]);
#pragma unroll
        for (int i = 0; i < 4; ++i)
#pragma unroll
          for (int j = 0; j < 4; ++j)
            acc[i][j] = __builtin_amdgcn_mfma_f32_16x16x32_bf16(
                a[i], bq[ks][j], acc[i][j], 0, 0, 0);
      }
    }

    // Epilogue: k = exp2(acc*S2 + ra + rb); fp32 partials, fp64 fold.
    f32x2 part01 = {0.f, 0.f}, part23 = {0.f, 0.f};
#pragma unroll
    for (int i = 0; i < 4; ++i) {
#pragma unroll
      for (int j = 0; j < 4; ++j) {
        const f32x2 rb2 = {cn[j], cn[j]};
        const f32x2 base01 = ar01[i] + rb2;
        const f32x2 base23 = ar23[i] + rb2;
        const f32x2 acc01 = {acc[i][j][0], acc[i][j][1]};
        const f32x2 acc23 = {acc[i][j][2], acc[i][j][3]};
        const f32x2 arg01 = __builtin_elementwise_fma(acc01, s2v, base01);
        const f32x2 arg23 = __builtin_elementwise_fma(acc23, s2v, base23);
        part01 += (f32x2){EXP2F(arg01.x), EXP2F(arg01.y)};
        part23 += (f32x2){EXP2F(arg23.x), EXP2F(arg23.y)};
      }
    }
    const f32x2 ps = part01 + part23;
    double w = ((I < 64) == (J < 64)) ? 1.0 : -1.0;
    if (I != J) w += w;
    local += w * (double)(ps.x + ps.y);

    // Walk to next tile.
    ++J;
    if (J >= TILES) { ++I; J = I; needA = true; }
  }

  // Block reduction + one global atomic.
#pragma unroll
  for (int o = 32; o > 0; o >>= 1) local += __shfl_down(local, o);
  if (lane == 0) red[wave] = local;
  __syncthreads();
  if (tid == 0) {
    atomicAdd(&sums[b & 63], red[0] + red[1] + red[2] + red[3]);
    __threadfence();
    const unsigned prev = atomicAdd(ctr, 1u);
    amLast = (prev == GRID - 1);
  }
  __syncthreads();
  if (amLast && wave == 0) {
    double v = atomicAdd(&sums[lane], 0.0);  // device-scope coherent read
#pragma unroll
    for (int o = 32; o > 0; o >>= 1) v += __shfl_down(v, o);
    if (lane == 0)
      out[0] = (float)(v * (1.0 / ((double)NN * (double)NN)));
  }
}

extern "C" void kernel_launch(void* const* d_in, const int* in_sizes, int n_in,
                              void* d_out, int out_size, void* d_ws, size_t ws_size,
                              hipStream_t stream) {
  const float* y_inputs = (const float*)d_in[0];  // "inputs"
  const float* x_true   = (const float*)d_in[1];  // "true_samples"
  float* out = (float*)d_out;

  char* ws = (char*)d_ws;
  double* sums = (double*)ws;                     // 64 fp64 partial slots
  unsigned* ctr = (unsigned*)(ws + WS_CTR);
  float* normZ = (float*)(ws + WS_NORM);
  __hip_bfloat16* Z = (__hip_bfloat16*)(ws + WS_Z);

  prep<<<TZ / 4, 256, 0, stream>>>(x_true, y_inputs, Z, normZ, sums, ctr);
  mmd_mfma<<<GRID, 256, 0, stream>>>(Z, normZ, sums, ctr, out);
}